// Round 1
// 9076.472 us; speedup vs baseline: 1.1684x; 1.1684x over previous
//
#include <hip/hip_runtime.h>
#include <hip/hip_bf16.h>

// Seq2seq LSTM (enc 1024 steps -> dec 1024 steps, reversed, proj-before-update).
// 16 WGs x 256 thr. 8 groups x 16 batches; 2 WGs/group each own 512 of the
// 1024 gate rows. f16 weight fragments persistent in VGPRs/AGPRs. Gates via
// mfma_f32_16x16x32_f16, K=320.
//
// Sync protocol (this version): NO threadfence / NO acquire fences.
// h is exchanged through device-scope RELAXED atomics (sc0 sc1 -> serviced at
// the Infinity Cache = device coherence point), so no buffer_wbl2 / buffer_inv
// is ever emitted. Release ordering = per-wave s_waitcnt vmcnt(0) before a
// relaxed agent atomicAdd on the WG flag (flag reaches 4*(t+1) when all 4
// waves drained). Consumer spins on a relaxed agent load (no L2 invalidate),
// then pulls partner h as relaxed u64 atomic loads.
// Critical-path order: own-half MFMAs BEFORE poll; decoder projection AFTER
// publish.

#define Bb 128
#define Tt 1024
#define Ff 64
#define Hh 256

typedef _Float16 h16;
typedef __attribute__((ext_vector_type(8))) _Float16 h16x8;
typedef __attribute__((ext_vector_type(4))) float f32x4;
typedef unsigned long long u64;

// ws layout (f16 element offsets)
#define WENC_OFF 0          // 2*4*8*10*64*8 = 327680 f16
#define WDEC_OFF 327680
#define WOUT_OFF 655360     // 2*2*8*64*8 = 16384 f16
#define HBUF_OFF 671744     // 16 wg * 2 slots * 16 m * 128 col = 65536 f16
#define FLAGS_BYTE_OFF 1474560  // (671744+65536)*2, u32[256] (64B stride per WG)

__device__ __forceinline__ float fast_sigmoid(float x) {
  float e = __expf(-fabsf(x));
  float s = __builtin_amdgcn_rcpf(1.f + e);
  return x >= 0.f ? s : 1.f - s;
}
__device__ __forceinline__ float fast_tanh(float x) {
  float e = __expf(-2.f * fabsf(x));
  float r = (1.f - e) * __builtin_amdgcn_rcpf(1.f + e);
  return x >= 0.f ? r : -r;
}
__device__ __forceinline__ h16x8 pack16(u64 lo, u64 hi) {
  union { u64 u[2]; h16x8 v; } x;
  x.u[0] = lo; x.u[1] = hi;
  return x.v;
}

// ---- prep: convert fp32 weights into f16 MFMA-fragment-ordered regions ----
__global__ void lstm_prep(const float* __restrict__ Wih_e, const float* __restrict__ Whh_e,
                          const float* __restrict__ Wih_d, const float* __restrict__ Whh_d,
                          const float* __restrict__ Wout, h16* __restrict__ ws16,
                          unsigned int* __restrict__ flags) {
  int e = blockIdx.x * 256 + threadIdx.x;
  if (e < 256) flags[e] = 0u;
  if (e < 655360) {
    int r = e;
    const float* Wih = Wih_e; const float* Whh = Whh_e;
    int off = WENC_OFF;
    if (r >= 327680) { r -= 327680; Wih = Wih_d; Whh = Whh_d; off = WDEC_OFF; }
    // r = ((((q*4+w)*8+nt)*10+kt)*64+lane)*8 + j
    int j    = r & 7;
    int lane = (r >> 3) & 63;
    int kt   = (r >> 9) % 10;
    int tmp  = (r >> 9) / 10;        // (q*4+w)*8+nt
    int nt   = tmp & 7;
    int w    = (tmp >> 3) & 3;
    int q    = tmp >> 5;
    int g = nt >> 1, ct = nt & 1;
    int col = q * 128 + w * 32 + ct * 16 + (lane & 15);
    int row = g * 256 + col;
    int k = kt * 32 + (lane >> 4) * 8 + j;
    float v = (k < 64) ? Wih[row * 64 + k] : Whh[row * 256 + (k - 64)];
    ws16[off + r] = (h16)v;
  } else if (e < 655360 + 16384) {
    int r = e - 655360;
    // r = (((q*2+wt)*8+kt)*64+lane)*8 + j
    int j    = r & 7;
    int lane = (r >> 3) & 63;
    int kt   = (r >> 9) & 7;
    int wt   = (r >> 12) & 1;
    int q    = (r >> 13) & 1;
    int f = q * 32 + wt * 16 + (lane & 15);
    int k = kt * 32 + (lane >> 4) * 8 + j;
    ws16[WOUT_OFF + r] = (h16)Wout[f * 256 + k];
  }
}

#define MFMA_KT(kt) do {                                                         \
    acc[0] = __builtin_amdgcn_mfma_f32_16x16x32_f16(a[kt], wf[0][kt], acc[0], 0, 0, 0); \
    acc[1] = __builtin_amdgcn_mfma_f32_16x16x32_f16(a[kt], wf[1][kt], acc[1], 0, 0, 0); \
    acc[2] = __builtin_amdgcn_mfma_f32_16x16x32_f16(a[kt], wf[2][kt], acc[2], 0, 0, 0); \
    acc[3] = __builtin_amdgcn_mfma_f32_16x16x32_f16(a[kt], wf[3][kt], acc[3], 0, 0, 0); \
    acc[4] = __builtin_amdgcn_mfma_f32_16x16x32_f16(a[kt], wf[4][kt], acc[4], 0, 0, 0); \
    acc[5] = __builtin_amdgcn_mfma_f32_16x16x32_f16(a[kt], wf[5][kt], acc[5], 0, 0, 0); \
    acc[6] = __builtin_amdgcn_mfma_f32_16x16x32_f16(a[kt], wf[6][kt], acc[6], 0, 0, 0); \
    acc[7] = __builtin_amdgcn_mfma_f32_16x16x32_f16(a[kt], wf[7][kt], acc[7], 0, 0, 0); \
  } while (0)

// ---- main persistent kernel ----
__global__ __launch_bounds__(256, 1) void lstm_main(
    const float* __restrict__ ts,
    const float* __restrict__ b_enc, const float* __restrict__ b_dec,
    const float* __restrict__ b_out,
    const h16* __restrict__ wsW, h16* __restrict__ hbuf,
    unsigned int* flags, float* __restrict__ out) {
  const int tid = threadIdx.x;
  const int wg = blockIdx.x;
  const int grp = wg & 7, q = wg >> 3;
  const int w = tid >> 6, lane = tid & 63;
  const int n16 = lane & 15, quad = lane >> 4;
  const int b0 = grp * 16;
  const int partner = wg ^ 8;

  __shared__ __align__(16) h16 xh[2][16][328];  // k: 0..63 x, 64..319 h
  __shared__ h16x8 woutLds[1024];               // 32-f slice of W_out frags

  // persistent weight fragments: 8 N-tiles x 10 K-tiles
  h16x8 wf[8][10];
  {
    const h16x8* wsrc = (const h16x8*)(wsW + WENC_OFF);
#pragma unroll
    for (int nt = 0; nt < 8; ++nt)
#pragma unroll
      for (int kt = 0; kt < 10; ++kt)
        wf[nt][kt] = wsrc[(((q * 4 + w) * 8 + nt) * 10 + kt) * 64 + lane];
  }
  float bias8[8];
#pragma unroll
  for (int nt = 0; nt < 8; ++nt) {
    int g = nt >> 1, ct = nt & 1;
    bias8[nt] = b_enc[g * 256 + q * 128 + w * 32 + ct * 16 + n16];
  }
  const float bo = b_out[q * 32 + w * 16 + n16];

  float c8[8];
#pragma unroll
  for (int i = 0; i < 8; ++i) c8[i] = 0.f;

  // zero h-region of xh[0]; stage x_0
  for (int i = tid; i < 16 * 264; i += 256) {
    int m = i / 264;
    xh[0][m][64 + (i - m * 264)] = (h16)0.f;
  }
  const int m_x = tid >> 4, ks_x = (tid & 15) * 4;
  {
    const f32x4 xv0 = *(const f32x4*)(ts + ((size_t)(b0 + m_x) * Tt + 0) * Ff + ks_x);
#pragma unroll
    for (int u = 0; u < 4; ++u) xh[0][m_x][ks_x + u] = (h16)xv0[u];
  }
  __syncthreads();

  for (int t = 0; t < 2048; ++t) {
    const int nb = t & 1, nxt = nb ^ 1;
    const bool dec = (t >= 1024);

    // phase switch: decoder weights + biases + W_out -> LDS (once)
    if (t == 1024) {
      const h16x8* wsrc2 = (const h16x8*)(wsW + WDEC_OFF);
#pragma unroll
      for (int nt = 0; nt < 8; ++nt)
#pragma unroll
        for (int kt = 0; kt < 10; ++kt)
          wf[nt][kt] = wsrc2[(((q * 4 + w) * 8 + nt) * 10 + kt) * 64 + lane];
#pragma unroll
      for (int nt = 0; nt < 8; ++nt) {
        int g = nt >> 1, ct = nt & 1;
        bias8[nt] = b_dec[g * 256 + q * 128 + w * 32 + ct * 16 + n16];
      }
      const h16x8* wo = (const h16x8*)(wsW + WOUT_OFF) + q * 1024;
      for (int i = tid; i < 1024; i += 256) woutLds[i] = wo[i];
      __syncthreads();
    }

    // (a) partner-independent A-fragments: x + own h-half from LDS
    h16x8 a[10];
    const h16* xrow = &xh[nb][n16][0];
    a[0] = *(const h16x8*)(xrow + 0 * 32 + quad * 8);
    a[1] = *(const h16x8*)(xrow + 1 * 32 + quad * 8);
    if (q == 0) {
      a[2] = *(const h16x8*)(xrow + 2 * 32 + quad * 8);
      a[3] = *(const h16x8*)(xrow + 3 * 32 + quad * 8);
      a[4] = *(const h16x8*)(xrow + 4 * 32 + quad * 8);
      a[5] = *(const h16x8*)(xrow + 5 * 32 + quad * 8);
    } else {
      a[6] = *(const h16x8*)(xrow + 6 * 32 + quad * 8);
      a[7] = *(const h16x8*)(xrow + 7 * 32 + quad * 8);
      a[8] = *(const h16x8*)(xrow + 8 * 32 + quad * 8);
      a[9] = *(const h16x8*)(xrow + 9 * 32 + quad * 8);
    }

    // (b) bias init + own-part MFMAs (48) -- runs while partner h is in flight
    f32x4 acc[8];
#pragma unroll
    for (int nt = 0; nt < 8; ++nt) {
      f32x4 v; v[0] = bias8[nt]; v[1] = bias8[nt]; v[2] = bias8[nt]; v[3] = bias8[nt];
      acc[nt] = v;
    }
    MFMA_KT(0); MFMA_KT(1);
    if (q == 0) { MFMA_KT(2); MFMA_KT(3); MFMA_KT(4); MFMA_KT(5); }
    else        { MFMA_KT(6); MFMA_KT(7); MFMA_KT(8); MFMA_KT(9); }

    // (c) prefetch x for step t+1
    f32x4 xv;
#pragma unroll
    for (int u = 0; u < 4; ++u) xv[u] = 0.f;
    if (t + 1 < 2048) {
      int xi = (t + 1 < 1024) ? (t + 1) : (2047 - (t + 1));
      xv = *(const f32x4*)(ts + ((size_t)(b0 + m_x) * Tt + xi) * Ff + ks_x);
    }

    // (d,e,f) partner h-half: poll (relaxed, no cache inv), pull, 32 MFMAs
    if (t > 0) {
      const unsigned int need = 4u * (unsigned int)t;
      while (__hip_atomic_load(&flags[partner * 16], __ATOMIC_RELAXED,
                               __HIP_MEMORY_SCOPE_AGENT) < need) { }
      asm volatile("" ::: "memory");
      const u64* ps64 = (const u64*)hbuf + ((size_t)partner * 2 + nxt) * 512;
      const int jb = (n16 * 16 + quad) * 2;
      u64 dl0 = __hip_atomic_load((u64*)(ps64 + jb + 0),  __ATOMIC_RELAXED, __HIP_MEMORY_SCOPE_AGENT);
      u64 dh0 = __hip_atomic_load((u64*)(ps64 + jb + 1),  __ATOMIC_RELAXED, __HIP_MEMORY_SCOPE_AGENT);
      u64 dl1 = __hip_atomic_load((u64*)(ps64 + jb + 8),  __ATOMIC_RELAXED, __HIP_MEMORY_SCOPE_AGENT);
      u64 dh1 = __hip_atomic_load((u64*)(ps64 + jb + 9),  __ATOMIC_RELAXED, __HIP_MEMORY_SCOPE_AGENT);
      u64 dl2 = __hip_atomic_load((u64*)(ps64 + jb + 16), __ATOMIC_RELAXED, __HIP_MEMORY_SCOPE_AGENT);
      u64 dh2 = __hip_atomic_load((u64*)(ps64 + jb + 17), __ATOMIC_RELAXED, __HIP_MEMORY_SCOPE_AGENT);
      u64 dl3 = __hip_atomic_load((u64*)(ps64 + jb + 24), __ATOMIC_RELAXED, __HIP_MEMORY_SCOPE_AGENT);
      u64 dh3 = __hip_atomic_load((u64*)(ps64 + jb + 25), __ATOMIC_RELAXED, __HIP_MEMORY_SCOPE_AGENT);
      if (q == 0) {
        a[6] = pack16(dl0, dh0); a[7] = pack16(dl1, dh1);
        a[8] = pack16(dl2, dh2); a[9] = pack16(dl3, dh3);
        MFMA_KT(6); MFMA_KT(7); MFMA_KT(8); MFMA_KT(9);
      } else {
        a[2] = pack16(dl0, dh0); a[3] = pack16(dl1, dh1);
        a[4] = pack16(dl2, dh2); a[5] = pack16(dl3, dh3);
        MFMA_KT(2); MFMA_KT(3); MFMA_KT(4); MFMA_KT(5);
      }
    }

    // (g) pointwise LSTM cell (fp32 c in regs)
    h16 hv[8];
#pragma unroll
    for (int ct = 0; ct < 2; ++ct)
#pragma unroll
      for (int r = 0; r < 4; ++r) {
        float i_ = fast_sigmoid(acc[0 + ct][r]);
        float f_ = fast_sigmoid(acc[2 + ct][r]);
        float g_ = fast_tanh(acc[4 + ct][r]);
        float o_ = fast_sigmoid(acc[6 + ct][r]);
        float cv = f_ * c8[ct * 4 + r] + i_ * g_;
        c8[ct * 4 + r] = cv;
        hv[ct * 4 + r] = (h16)(o_ * fast_tanh(cv));
      }

    // (h1) write h -> xh[nxt] own half; stage x_{t+1}
#pragma unroll
    for (int ct = 0; ct < 2; ++ct)
#pragma unroll
      for (int r = 0; r < 4; ++r) {
        int m = quad * 4 + r;
        int colLocal = w * 32 + ct * 16 + n16;
        xh[nxt][m][64 + q * 128 + colLocal] = hv[ct * 4 + r];
      }
    if (t + 1 < 2048) {
#pragma unroll
      for (int u = 0; u < 4; ++u) xh[nxt][m_x][ks_x + u] = (h16)xv[u];
    }

    // (h2) single barrier per step
    __syncthreads();

    // (h3,h4) publish own h-half: coalesced relaxed u64 device-scope stores
    // from LDS, per-wave vmcnt drain, per-wave flag increment (no fences).
    if (t < 2047) {
      u64* hb64 = (u64*)hbuf + ((size_t)wg * 2 + nb) * 512;
#pragma unroll
      for (int r2 = 0; r2 < 2; ++r2) {
        const int k = tid + r2 * 256;
        const int mm = k >> 5, c4 = k & 31;
        u64 v = *(const u64*)(&xh[nxt][mm][64 + q * 128 + c4 * 4]);
        __hip_atomic_store(hb64 + k, v, __ATOMIC_RELAXED, __HIP_MEMORY_SCOPE_AGENT);
      }
      asm volatile("s_waitcnt vmcnt(0)" ::: "memory");
      if (lane == 0)
        __hip_atomic_fetch_add(&flags[wg * 16], 1u, __ATOMIC_RELAXED,
                               __HIP_MEMORY_SCOPE_AGENT);
    }

    // (h5) decoder output projection (PRE-update h = a[2..9]) -- off the
    // critical path, after publish
    if (dec && w < 2) {
      f32x4 ao; ao[0] = bo; ao[1] = bo; ao[2] = bo; ao[3] = bo;
#pragma unroll
      for (int kt = 0; kt < 8; ++kt)
        ao = __builtin_amdgcn_mfma_f32_16x16x32_f16(a[2 + kt], woutLds[(w * 8 + kt) * 64 + lane], ao, 0, 0, 0);
      int tpos = 2047 - t;
      int f = q * 32 + w * 16 + n16;
#pragma unroll
      for (int r = 0; r < 4; ++r) {
        int m = quad * 4 + r;
        out[((size_t)(b0 + m) * Tt + tpos) * Ff + f] = ao[r];
      }
    }
  }
}

extern "C" void kernel_launch(void* const* d_in, const int* in_sizes, int n_in,
                              void* d_out, int out_size, void* d_ws, size_t ws_size,
                              hipStream_t stream) {
  const float* ts  = (const float*)d_in[0];
  const float* Wie = (const float*)d_in[1];
  const float* Whe = (const float*)d_in[2];
  const float* be  = (const float*)d_in[3];
  const float* Wid = (const float*)d_in[4];
  const float* Whd = (const float*)d_in[5];
  const float* bd  = (const float*)d_in[6];
  const float* Wo  = (const float*)d_in[7];
  const float* bo  = (const float*)d_in[8];

  h16* ws16 = (h16*)d_ws;
  unsigned int* flags = (unsigned int*)((char*)d_ws + FLAGS_BYTE_OFF);
  float* out = (float*)d_out;

  // total ws use: ~1.44 MB + 1 KB flags
  lstm_prep<<<2624, 256, 0, stream>>>(Wie, Whe, Wid, Whd, Wo, ws16, flags);
  lstm_main<<<16, 256, 0, stream>>>(ts, be, bd, bo, ws16, ws16 + HBUF_OFF, flags, out);
}